// Round 1
// baseline (201.412 us; speedup 1.0000x reference)
//
#include <hip/hip_runtime.h>
#include <hip/hip_bf16.h>
#include <cmath>

typedef _Float16 half_t;
typedef half_t half4 __attribute__((ext_vector_type(4)));
typedef half_t half8 __attribute__((ext_vector_type(8)));
typedef float f32x4 __attribute__((ext_vector_type(4)));

#define N_HEADS 16
#define HD      64
#define T_SEQ   2048
#define B_SZ    2
#define C_DIM   1024
#define M_ROWS  (B_SZ * T_SEQ)   /* 4096 */
#define N_QKV   (3 * C_DIM)      /* 3072 */
#define QSCALE  0.18033688f      /* 0.125 * log2(e), folded into Q at rope */

__device__ inline void load_lds16(const half_t* g, half_t* l) {
  __builtin_amdgcn_global_load_lds(
      (const __attribute__((address_space(1))) void*)g,
      (__attribute__((address_space(3))) void*)l, 16, 0, 0);
}

// ---- fused prep: x->f16 cvt (blocks 0..4095), w_attn^T (..4863), w_proj^T ----
__global__ __launch_bounds__(256) void k_prep(const float* __restrict__ x,
                                              half_t* __restrict__ xb,
                                              const float* __restrict__ wa,
                                              half_t* __restrict__ wT,
                                              const float* __restrict__ wp,
                                              half_t* __restrict__ wpT) {
  __shared__ float tile[64][65];
  int bid = blockIdx.x, tid = threadIdx.x;
  if (bid < 4096) {
    int i = (bid * 256 + tid) * 4;
    float4 v = *(const float4*)(x + i);
    half_t o[4] = {(half_t)v.x, (half_t)v.y, (half_t)v.z, (half_t)v.w};
    *(ulong1*)(xb + i) = *(ulong1*)o;
    return;
  }
  const float* in; half_t* out; int K, N, id;
  if (bid < 4096 + 768) { id = bid - 4096; in = wa; out = wT;  K = 1024; N = 3072; }
  else                  { id = bid - 4864; in = wp; out = wpT; K = 1024; N = 1024; }
  int n0 = (id % (N / 64)) * 64, k0 = (id / (N / 64)) * 64;
  int tx = tid & 63, ty = tid >> 6;
  #pragma unroll
  for (int i = 0; i < 64; i += 4)
    tile[ty + i][tx] = in[(size_t)(k0 + ty + i) * N + n0 + tx];
  __syncthreads();
  #pragma unroll
  for (int i = 0; i < 64; i += 4) {
    int r = ty + i;
    out[(size_t)(n0 + r) * K + k0 + tx] = (half_t)tile[tx][r];
  }
}

// ------------- GEMM: C = A(f16,[M][K]) * Bt(f16,[N][K])^T + bias, OT out ----
// 128xTN tile, BK=64, global_load_lds width-16 into XOR-swizzled LDS.
template <typename OT, int TN>
__global__ __launch_bounds__(256) void k_gemm(const half_t* __restrict__ A,
                                              const half_t* __restrict__ Bt,
                                              const float* __restrict__ bias,
                                              OT* __restrict__ C,
                                              int M, int N, int K) {
  constexpr int NI = TN / 32;          // n-fragments per wave
  __shared__ half_t As[128 * 64];
  __shared__ half_t Bs[TN * 64];
  int tid = threadIdx.x;
  int wave = tid >> 6, lane = tid & 63;
  int lane15 = lane & 15, quad = lane >> 4;
  int wm = (wave >> 1) * 64, wn = (wave & 1) * (TN / 2);
  int bm0 = blockIdx.y * 128, bn0 = blockIdx.x * TN;
  f32x4 acc[4][NI] = {};

  for (int kb = 0; kb < K; kb += 64) {
    const half_t* Ag = A + (size_t)bm0 * K + kb;
    const half_t* Bg = Bt + (size_t)bn0 * K + kb;
    __syncthreads();
    #pragma unroll
    for (int p = 0; p < 4; p++) {
      int fc = wave * 4 * 64 + p * 64 + lane;
      int r = fc >> 3, c = (fc & 7) ^ (r & 7);
      load_lds16(Ag + (size_t)r * K + c * 8, As + (wave * 4 + p) * 512);
    }
    #pragma unroll
    for (int p = 0; p < NI; p++) {
      int fc = wave * NI * 64 + p * 64 + lane;
      int r = fc >> 3, c = (fc & 7) ^ (r & 7);
      load_lds16(Bg + (size_t)r * K + c * 8, Bs + (wave * NI + p) * 512);
    }
    __syncthreads();
    #pragma unroll
    for (int ks = 0; ks < 2; ks++) {
      half8 af[4], bf[NI];
      #pragma unroll
      for (int i = 0; i < 4; i++) {
        int Ra = wm + i * 16 + lane15;
        af[i] = *(const half8*)(As + Ra * 64 + ((ks * 4 + quad) ^ (Ra & 7)) * 8);
      }
      #pragma unroll
      for (int i = 0; i < NI; i++) {
        int Rb = wn + i * 16 + lane15;
        bf[i] = *(const half8*)(Bs + Rb * 64 + ((ks * 4 + quad) ^ (Rb & 7)) * 8);
      }
      #pragma unroll
      for (int mi = 0; mi < 4; mi++)
        #pragma unroll
        for (int ni = 0; ni < NI; ni++)
          acc[mi][ni] = __builtin_amdgcn_mfma_f32_16x16x32_f16(af[mi], bf[ni], acc[mi][ni], 0, 0, 0);
    }
  }
  #pragma unroll
  for (int mi = 0; mi < 4; mi++)
    #pragma unroll
    for (int ni = 0; ni < NI; ni++) {
      int n = bn0 + wn + ni * 16 + lane15;
      float bv = bias[n];
      int mrow = bm0 + wm + mi * 16 + quad * 4;
      #pragma unroll
      for (int r = 0; r < 4; r++)
        C[(size_t)(mrow + r) * N + n] = (OT)(acc[mi][ni][r] + bv);
    }
}

// ------------- RoPE + reorg (qkv f16); Q pre-scaled by 0.125*log2(e) -------------
__global__ __launch_bounds__(256) void k_rope(const half_t* __restrict__ qkv,
                                              half_t* __restrict__ Q,
                                              half_t* __restrict__ Ko,
                                              half_t* __restrict__ Vt) {
  __shared__ float vt[64][65];
  int bh = blockIdx.y;
  int b = bh >> 4, h = bh & 15;
  int t0 = blockIdx.x * 64;
  int tid = threadIdx.x;
  int trow = tid >> 5, i = tid & 31;           // 8 t-rows x 32 freq
  float inv = exp2f(-(float)i * (13.287712379549449f / 32.0f));
  #pragma unroll
  for (int p = 0; p < 8; p++) {
    int tloc = p * 8 + trow;
    int t = t0 + tloc;
    const half_t* row = qkv + (size_t)(b * T_SEQ + t) * N_QKV;
    float q1 = (float)row[h * 64 + i],        q2 = (float)row[h * 64 + i + 32];
    float k1 = (float)row[1024 + h * 64 + i], k2 = (float)row[1024 + h * 64 + i + 32];
    float v1 = (float)row[2048 + h * 64 + i], v2 = (float)row[2048 + h * 64 + i + 32];
    float s, c;
    sincosf((float)t * inv, &s, &c);
    size_t base = ((size_t)bh * T_SEQ + t) * HD;
    Q[base + i]       = (half_t)((q1 * c - q2 * s) * QSCALE);
    Q[base + i + 32]  = (half_t)((q1 * s + q2 * c) * QSCALE);
    Ko[base + i]      = (half_t)(k1 * c - k2 * s);
    Ko[base + i + 32] = (half_t)(k1 * s + k2 * c);
    vt[i][tloc]      = v1;
    vt[i + 32][tloc] = v2;
  }
  __syncthreads();
  int d = tid >> 6, tc = tid & 63;             // 4 d-rows x 64 t
  #pragma unroll
  for (int p = 0; p < 16; p++) {
    int dd = p * 4 + d;
    Vt[((size_t)bh * HD + dd) * T_SEQ + t0 + tc] = (half_t)vt[dd][tc];
  }
}

// ------------- causal flash: 128-q blocks, 8 waves, uniform CU balance -------------
// grid (16, B*H): ONE 128-q tile per block; 512 blocks = 2/CU = 4 waves/SIMD,
// STEADY for the whole kernel (the old 64-q version started at 4 blocks/CU but
// decayed as short blocks finished -> measured 25% occupancy).
// Dispatch fact (measured R9): linear ID = x + gridX*y, CU = linear % 256, so the
// 2 co-resident blocks of a CU are (x,y) and (x,y+16). qt = (bh<16) ? x : 15-x
// gives per-bh bijection and per-CU trip sum (2x+2)+(32-2x) = 34 for EVERY x ->
// perfect balance, no tail. Each staged 64-kv tile feeds 128 q-rows: staging
// traffic and per-wave staging instructions HALVED vs the 64-q version.
// K/V double-buffered in XOR-swizzled LDS via global_load_lds; two diagonal
// tiles peeled (hot loop mask-free); max-free softmax.
__global__ __launch_bounds__(512) void k_flash(const half_t* __restrict__ Qg,
                                               const half_t* __restrict__ Kg,
                                               const half_t* __restrict__ Vg,
                                               half_t* __restrict__ y) {
  __shared__ half_t Ks[2][4096];
  __shared__ half_t Vs[2][4096];
  int bh = blockIdx.y;
  int b = bh >> 4, h = bh & 15;
  int qt = (bh < 16) ? (int)blockIdx.x : 15 - (int)blockIdx.x;
  int tid = threadIdx.x;
  int wave = tid >> 6, lane = tid & 63;
  int lane15 = lane & 15, quad = lane >> 4;
  const half_t* Qb = Qg + (size_t)bh * T_SEQ * HD;
  const half_t* Kb = Kg + (size_t)bh * T_SEQ * HD;
  const half_t* Vb = Vg + (size_t)bh * HD * T_SEQ;

  // 8 waves x 64 lanes x 16B = 8KB = one full 64x64 f16 tile per buffer.
  #define STAGE(buf, kv0)                                                      \
    {                                                                          \
      int fc = wave * 64 + lane;                                               \
      int rr = fc >> 3, cc = (fc & 7) ^ (rr & 7);                              \
      load_lds16(Kb + (size_t)((kv0) + rr) * HD + cc * 8,                      \
                 &Ks[buf][0] + fc * 8);                                        \
      load_lds16(Vb + (size_t)rr * T_SEQ + (kv0) + cc * 8,                     \
                 &Vs[buf][0] + fc * 8);                                        \
    }

  int q0 = qt * 128;
  int qrow = q0 + wave * 16 + lane15;      // this wave's q column (S^T B-op n)
  half8 bq0 = *(const half8*)(Qb + (size_t)qrow * HD + quad * 8);
  half8 bq1 = *(const half8*)(Qb + (size_t)qrow * HD + 32 + quad * 8);
  f32x4 ot[4] = {};                        // O^T: d = nm*16+quad*4+r, q = lane15
  float l = 0.f;

  STAGE(0, 0);
  // ---- hot loop: 2*qt off-diagonal tiles, no mask code ----
  for (int j = 0; j < 2 * qt; j++) {
    int buf = j & 1;
    __syncthreads();                       // stage(j) DMA drained & visible
    STAGE(buf ^ 1, (j + 1) * 64);          // prefetch overlaps compute
    const half_t* Kt = &Ks[buf][0];
    const half_t* Vt = &Vs[buf][0];
    f32x4 sacc[4];
    #pragma unroll
    for (int s = 0; s < 4; s++) {
      int R = s * 16 + lane15;
      half8 ak0 = *(const half8*)(Kt + R * 64 + ((quad) ^ (R & 7)) * 8);
      half8 ak1 = *(const half8*)(Kt + R * 64 + ((4 + quad) ^ (R & 7)) * 8);
      f32x4 z = {};
      z = __builtin_amdgcn_mfma_f32_16x16x32_f16(ak0, bq0, z, 0, 0, 0);
      sacc[s] = __builtin_amdgcn_mfma_f32_16x16x32_f16(ak1, bq1, z, 0, 0, 0);
    }
    #pragma unroll
    for (int s = 0; s < 4; s++) {
      half4 bp;
      #pragma unroll
      for (int r = 0; r < 4; r++) {
        float p = exp2f(fminf(sacc[s][r], 14.0f));
        l += p;
        bp[r] = (half_t)p;
      }
      #pragma unroll
      for (int nm = 0; nm < 4; nm++) {
        int Rv = nm * 16 + lane15;
        half4 av = *(const half4*)(Vt + Rv * 64 +
                                   ((2 * s + (quad >> 1)) ^ (Rv & 7)) * 8 +
                                   (quad & 1) * 4);
        ot[nm] = __builtin_amdgcn_mfma_f32_16x16x16f16(av, bp, ot[nm], 0, 0, 0);
      }
    }
  }
  // ---- peeled diagonal tile #1 (j = 2*qt): waves 0-3 masked, 4-7 full ----
  // qloc = wave*16+lane15 in [0,128); kvloc in [0,64) -> waves 4-7 auto-pass.
  {
    int j = 2 * qt;
    int buf = j & 1;
    __syncthreads();
    STAGE(buf ^ 1, (j + 1) * 64);          // prefetch tile 2*qt+1
    const half_t* Kt = &Ks[buf][0];
    const half_t* Vt = &Vs[buf][0];
    f32x4 sacc[4];
    #pragma unroll
    for (int s = 0; s < 4; s++) {
      int R = s * 16 + lane15;
      half8 ak0 = *(const half8*)(Kt + R * 64 + ((quad) ^ (R & 7)) * 8);
      half8 ak1 = *(const half8*)(Kt + R * 64 + ((4 + quad) ^ (R & 7)) * 8);
      f32x4 z = {};
      z = __builtin_amdgcn_mfma_f32_16x16x32_f16(ak0, bq0, z, 0, 0, 0);
      sacc[s] = __builtin_amdgcn_mfma_f32_16x16x32_f16(ak1, bq1, z, 0, 0, 0);
    }
    #pragma unroll
    for (int s = 0; s < 4; s++) {
      half4 bp;
      #pragma unroll
      for (int r = 0; r < 4; r++) {
        float sv = sacc[s][r];
        if (s * 16 + quad * 4 + r > wave * 16 + lane15) sv = -1.0e30f;
        float p = exp2f(fminf(sv, 14.0f));
        l += p;
        bp[r] = (half_t)p;
      }
      #pragma unroll
      for (int nm = 0; nm < 4; nm++) {
        int Rv = nm * 16 + lane15;
        half4 av = *(const half4*)(Vt + Rv * 64 +
                                   ((2 * s + (quad >> 1)) ^ (Rv & 7)) * 8 +
                                   (quad & 1) * 4);
        ot[nm] = __builtin_amdgcn_mfma_f32_16x16x16f16(av, bp, ot[nm], 0, 0, 0);
      }
    }
  }
  // ---- peeled diagonal tile #2 (j = 2*qt+1): only waves 4-7 (fully masked
  // for waves 0-3, so they skip compute entirely) ----
  {
    int j = 2 * qt + 1;
    int buf = j & 1;
    __syncthreads();                       // all waves: barrier + DMA drain
    if (wave >= 4) {
      const half_t* Kt = &Ks[buf][0];
      const half_t* Vt = &Vs[buf][0];
      f32x4 sacc[4];
      #pragma unroll
      for (int s = 0; s < 4; s++) {
        int R = s * 16 + lane15;
        half8 ak0 = *(const half8*)(Kt + R * 64 + ((quad) ^ (R & 7)) * 8);
        half8 ak1 = *(const half8*)(Kt + R * 64 + ((4 + quad) ^ (R & 7)) * 8);
        f32x4 z = {};
        z = __builtin_amdgcn_mfma_f32_16x16x32_f16(ak0, bq0, z, 0, 0, 0);
        sacc[s] = __builtin_amdgcn_mfma_f32_16x16x32_f16(ak1, bq1, z, 0, 0, 0);
      }
      #pragma unroll
      for (int s = 0; s < 4; s++) {
        half4 bp;
        #pragma unroll
        for (int r = 0; r < 4; r++) {
          float sv = sacc[s][r];
          if (s * 16 + quad * 4 + r > (wave - 4) * 16 + lane15) sv = -1.0e30f;
          float p = exp2f(fminf(sv, 14.0f));
          l += p;
          bp[r] = (half_t)p;
        }
        #pragma unroll
        for (int nm = 0; nm < 4; nm++) {
          int Rv = nm * 16 + lane15;
          half4 av = *(const half4*)(Vt + Rv * 64 +
                                     ((2 * s + (quad >> 1)) ^ (Rv & 7)) * 8 +
                                     (quad & 1) * 4);
          ot[nm] = __builtin_amdgcn_mfma_f32_16x16x16f16(av, bp, ot[nm], 0, 0, 0);
        }
      }
    }
  }

  // l: sum across the 4 quads holding this q-column, then write y
  l += __shfl_xor(l, 16);
  l += __shfl_xor(l, 32);
  float invl = 1.0f / l;
  int t = q0 + wave * 16 + lane15;
  half_t* yr = y + (size_t)(b * T_SEQ + t) * C_DIM + h * 64;
  #pragma unroll
  for (int nm = 0; nm < 4; nm++) {
    half4 o4;
    #pragma unroll
    for (int r = 0; r < 4; r++) o4[r] = (half_t)(ot[nm][r] * invl);
    *(half4*)(yr + nm * 16 + quad * 4) = o4;   // 8B store
  }
  #undef STAGE
}

extern "C" void kernel_launch(void* const* d_in, const int* in_sizes, int n_in,
                              void* d_out, int out_size, void* d_ws, size_t ws_size,
                              hipStream_t stream) {
  const float* x      = (const float*)d_in[0];
  const float* w_attn = (const float*)d_in[1];
  const float* b_attn = (const float*)d_in[2];
  const float* w_proj = (const float*)d_in[3];
  const float* b_proj = (const float*)d_in[4];
  float* out = (float*)d_out;

  char* ws = (char*)d_ws;
  const size_t MB = 1u << 20;
  half_t* xb  = (half_t*)(ws);             // 8 MB  x in f16
  half_t* wT  = (half_t*)(ws + 8 * MB);    // 6 MB  w_attn^T f16 [3072][1024]
  half_t* wpT = (half_t*)(ws + 14 * MB);   // 2 MB  w_proj^T f16 [1024][1024]
  half_t* Q   = (half_t*)(ws + 16 * MB);   // 8 MB  [bh][t][d]  (pre-scaled)
  half_t* Kb  = (half_t*)(ws + 24 * MB);   // 8 MB  [bh][t][d]
  half_t* Vt  = (half_t*)(ws + 32 * MB);   // 8 MB  [bh][d][t]
  half_t* qkv = (half_t*)(ws + 40 * MB);   // 24 MB f16 qkv
  half_t* y   = (half_t*)(ws + 40 * MB);   // aliases qkv (dead after k_rope)

  k_prep<<<4096 + 768 + 256, 256, 0, stream>>>(x, xb, w_attn, wT, w_proj, wpT);
  k_gemm<half_t, 128><<<dim3(N_QKV / 128, M_ROWS / 128), 256, 0, stream>>>(
      xb, wT, b_attn, qkv, M_ROWS, N_QKV, C_DIM);
  k_rope<<<dim3(T_SEQ / 64, B_SZ * N_HEADS), 256, 0, stream>>>(qkv, Q, Kb, Vt);
  k_flash<<<dim3(16, B_SZ * N_HEADS), 512, 0, stream>>>(Q, Kb, Vt, y);
  k_gemm<float, 64><<<dim3(C_DIM / 64, M_ROWS / 128), 256, 0, stream>>>(
      y, wpT, b_proj, out, M_ROWS, C_DIM, C_DIM);
}

// Round 2
// 194.391 us; speedup vs baseline: 1.0361x; 1.0361x over previous
//
#include <hip/hip_runtime.h>
#include <hip/hip_bf16.h>
#include <cmath>

typedef _Float16 half_t;
typedef half_t half4 __attribute__((ext_vector_type(4)));
typedef half_t half8 __attribute__((ext_vector_type(8)));
typedef float f32x4 __attribute__((ext_vector_type(4)));

#define N_HEADS 16
#define HD      64
#define T_SEQ   2048
#define B_SZ    2
#define C_DIM   1024
#define M_ROWS  (B_SZ * T_SEQ)   /* 4096 */
#define N_QKV   (3 * C_DIM)      /* 3072 */
#define QSCALE  0.18033688f      /* 0.125 * log2(e), folded into Q at rope */

__device__ inline void load_lds16(const half_t* g, half_t* l) {
  __builtin_amdgcn_global_load_lds(
      (const __attribute__((address_space(1))) void*)g,
      (__attribute__((address_space(3))) void*)l, 16, 0, 0);
}

// ---- fused prep: x->f16 cvt (blocks 0..4095), w_attn^T (..4863), w_proj^T ----
__global__ __launch_bounds__(256) void k_prep(const float* __restrict__ x,
                                              half_t* __restrict__ xb,
                                              const float* __restrict__ wa,
                                              half_t* __restrict__ wT,
                                              const float* __restrict__ wp,
                                              half_t* __restrict__ wpT) {
  __shared__ float tile[64][65];
  int bid = blockIdx.x, tid = threadIdx.x;
  if (bid < 4096) {
    int i = (bid * 256 + tid) * 4;
    float4 v = *(const float4*)(x + i);
    half_t o[4] = {(half_t)v.x, (half_t)v.y, (half_t)v.z, (half_t)v.w};
    *(ulong1*)(xb + i) = *(ulong1*)o;
    return;
  }
  const float* in; half_t* out; int K, N, id;
  if (bid < 4096 + 768) { id = bid - 4096; in = wa; out = wT;  K = 1024; N = 3072; }
  else                  { id = bid - 4864; in = wp; out = wpT; K = 1024; N = 1024; }
  int n0 = (id % (N / 64)) * 64, k0 = (id / (N / 64)) * 64;
  int tx = tid & 63, ty = tid >> 6;
  #pragma unroll
  for (int i = 0; i < 64; i += 4)
    tile[ty + i][tx] = in[(size_t)(k0 + ty + i) * N + n0 + tx];
  __syncthreads();
  #pragma unroll
  for (int i = 0; i < 64; i += 4) {
    int r = ty + i;
    out[(size_t)(n0 + r) * K + k0 + tx] = (half_t)tile[tx][r];
  }
}

// ------------- GEMM: C = A(f16,[M][K]) * Bt(f16,[N][K])^T + bias, OT out ----
// 128xTN tile, BK=64, global_load_lds width-16 into XOR-swizzled LDS.
template <typename OT, int TN>
__global__ __launch_bounds__(256) void k_gemm(const half_t* __restrict__ A,
                                              const half_t* __restrict__ Bt,
                                              const float* __restrict__ bias,
                                              OT* __restrict__ C,
                                              int M, int N, int K) {
  constexpr int NI = TN / 32;          // n-fragments per wave
  __shared__ half_t As[128 * 64];
  __shared__ half_t Bs[TN * 64];
  int tid = threadIdx.x;
  int wave = tid >> 6, lane = tid & 63;
  int lane15 = lane & 15, quad = lane >> 4;
  int wm = (wave >> 1) * 64, wn = (wave & 1) * (TN / 2);
  int bm0 = blockIdx.y * 128, bn0 = blockIdx.x * TN;
  f32x4 acc[4][NI] = {};

  for (int kb = 0; kb < K; kb += 64) {
    const half_t* Ag = A + (size_t)bm0 * K + kb;
    const half_t* Bg = Bt + (size_t)bn0 * K + kb;
    __syncthreads();
    #pragma unroll
    for (int p = 0; p < 4; p++) {
      int fc = wave * 4 * 64 + p * 64 + lane;
      int r = fc >> 3, c = (fc & 7) ^ (r & 7);
      load_lds16(Ag + (size_t)r * K + c * 8, As + (wave * 4 + p) * 512);
    }
    #pragma unroll
    for (int p = 0; p < NI; p++) {
      int fc = wave * NI * 64 + p * 64 + lane;
      int r = fc >> 3, c = (fc & 7) ^ (r & 7);
      load_lds16(Bg + (size_t)r * K + c * 8, Bs + (wave * NI + p) * 512);
    }
    __syncthreads();
    #pragma unroll
    for (int ks = 0; ks < 2; ks++) {
      half8 af[4], bf[NI];
      #pragma unroll
      for (int i = 0; i < 4; i++) {
        int Ra = wm + i * 16 + lane15;
        af[i] = *(const half8*)(As + Ra * 64 + ((ks * 4 + quad) ^ (Ra & 7)) * 8);
      }
      #pragma unroll
      for (int i = 0; i < NI; i++) {
        int Rb = wn + i * 16 + lane15;
        bf[i] = *(const half8*)(Bs + Rb * 64 + ((ks * 4 + quad) ^ (Rb & 7)) * 8);
      }
      #pragma unroll
      for (int mi = 0; mi < 4; mi++)
        #pragma unroll
        for (int ni = 0; ni < NI; ni++)
          acc[mi][ni] = __builtin_amdgcn_mfma_f32_16x16x32_f16(af[mi], bf[ni], acc[mi][ni], 0, 0, 0);
    }
  }
  #pragma unroll
  for (int mi = 0; mi < 4; mi++)
    #pragma unroll
    for (int ni = 0; ni < NI; ni++) {
      int n = bn0 + wn + ni * 16 + lane15;
      float bv = bias[n];
      int mrow = bm0 + wm + mi * 16 + quad * 4;
      #pragma unroll
      for (int r = 0; r < 4; r++)
        C[(size_t)(mrow + r) * N + n] = (OT)(acc[mi][ni][r] + bv);
    }
}

// ------------- RoPE + reorg (qkv f16); Q pre-scaled by 0.125*log2(e) -------------
__global__ __launch_bounds__(256) void k_rope(const half_t* __restrict__ qkv,
                                              half_t* __restrict__ Q,
                                              half_t* __restrict__ Ko,
                                              half_t* __restrict__ Vt) {
  __shared__ float vt[64][65];
  int bh = blockIdx.y;
  int b = bh >> 4, h = bh & 15;
  int t0 = blockIdx.x * 64;
  int tid = threadIdx.x;
  int trow = tid >> 5, i = tid & 31;           // 8 t-rows x 32 freq
  float inv = exp2f(-(float)i * (13.287712379549449f / 32.0f));
  #pragma unroll
  for (int p = 0; p < 8; p++) {
    int tloc = p * 8 + trow;
    int t = t0 + tloc;
    const half_t* row = qkv + (size_t)(b * T_SEQ + t) * N_QKV;
    float q1 = (float)row[h * 64 + i],        q2 = (float)row[h * 64 + i + 32];
    float k1 = (float)row[1024 + h * 64 + i], k2 = (float)row[1024 + h * 64 + i + 32];
    float v1 = (float)row[2048 + h * 64 + i], v2 = (float)row[2048 + h * 64 + i + 32];
    float s, c;
    sincosf((float)t * inv, &s, &c);
    size_t base = ((size_t)bh * T_SEQ + t) * HD;
    Q[base + i]       = (half_t)((q1 * c - q2 * s) * QSCALE);
    Q[base + i + 32]  = (half_t)((q1 * s + q2 * c) * QSCALE);
    Ko[base + i]      = (half_t)(k1 * c - k2 * s);
    Ko[base + i + 32] = (half_t)(k1 * s + k2 * c);
    vt[i][tloc]      = v1;
    vt[i + 32][tloc] = v2;
  }
  __syncthreads();
  int d = tid >> 6, tc = tid & 63;             // 4 d-rows x 64 t
  #pragma unroll
  for (int p = 0; p < 16; p++) {
    int dd = p * 4 + d;
    Vt[((size_t)bh * HD + dd) * T_SEQ + t0 + tc] = (half_t)vt[dd][tc];
  }
}

// ------------- causal flash: kv-split-2, uniform 17 rounds per block -------------
// R1 lesson: blocks progress independently (latency-bound), so per-BLOCK trip
// uniformity is what matters, not per-CU sums. Critical path was 32 rounds.
// New structure: 64-q tiles, 8 waves. Waves 0-3 (group 0) compute EVEN kv
// tiles, waves 4-7 (group 1) ODD kv tiles; partial (O,l) simply ADD (softmax
// is max-free) -> combine once per tile via LDS. Each block does q-tiles x and
// 31-x sequentially: rounds = ceil((x+1)/2)+ceil((32-x)/2) = 17 for EVERY x.
// Grid (16,32) = 512 blocks x 8 waves = 2 blocks/CU = 16 waves/CU, steady,
// no tail. Sequential depth 32 -> 17 at equal wave concurrency.
// LDS: 2 buf x 2 groups x (K 8KB + V 8KB) = 64 KB -> exactly 2 blocks/CU.
// Hot loop mask-free; last round of each tile: {diag, skip} per group.
__device__ __forceinline__ void sched_noop() {}

template <bool DIAG>
__device__ __forceinline__ void tile_mfma(const half_t* __restrict__ Kt,
                                          const half_t* __restrict__ Vt,
                                          half8 bq0, half8 bq1,
                                          f32x4 (&ot)[4], float& l,
                                          int lane15, int quad, int qloc) {
  f32x4 sacc[4];
  #pragma unroll
  for (int s = 0; s < 4; s++) {
    int R_ = s * 16 + lane15;
    half8 ak0 = *(const half8*)(Kt + R_ * 64 + ((quad) ^ (R_ & 7)) * 8);
    half8 ak1 = *(const half8*)(Kt + R_ * 64 + ((4 + quad) ^ (R_ & 7)) * 8);
    f32x4 z = {};
    z = __builtin_amdgcn_mfma_f32_16x16x32_f16(ak0, bq0, z, 0, 0, 0);
    sacc[s] = __builtin_amdgcn_mfma_f32_16x16x32_f16(ak1, bq1, z, 0, 0, 0);
  }
  #pragma unroll
  for (int s = 0; s < 4; s++) {
    half4 bp;
    #pragma unroll
    for (int r = 0; r < 4; r++) {
      float sv = sacc[s][r];
      if (DIAG && (s * 16 + quad * 4 + r > qloc)) sv = -1.0e30f;
      float p = exp2f(fminf(sv, 14.0f));
      l += p;
      bp[r] = (half_t)p;
    }
    #pragma unroll
    for (int nm = 0; nm < 4; nm++) {
      int Rv = nm * 16 + lane15;
      half4 av = *(const half4*)(Vt + Rv * 64 +
                                 ((2 * s + (quad >> 1)) ^ (Rv & 7)) * 8 +
                                 (quad & 1) * 4);
      ot[nm] = __builtin_amdgcn_mfma_f32_16x16x16f16(av, bp, ot[nm], 0, 0, 0);
    }
  }
}

// stage kv tiles (j0 for group 0, j1 for group 1) of K and V into buffer bb;
// all 8 waves cooperate: each wave loads 1KB of each of the 4 sub-tiles.
#define STAGE2(bb, j0, j1)                                                     \
  {                                                                            \
    int fc = wave * 64 + lane;                                                 \
    int rr_ = fc >> 3, cc = (fc & 7) ^ (rr_ & 7);                              \
    load_lds16(Kb + (size_t)((j0) * 64 + rr_) * HD + cc * 8,                   \
               &Ks[bb][0][0] + fc * 8);                                        \
    load_lds16(Kb + (size_t)((j1) * 64 + rr_) * HD + cc * 8,                   \
               &Ks[bb][1][0] + fc * 8);                                        \
    load_lds16(Vb + (size_t)rr_ * T_SEQ + (j0) * 64 + cc * 8,                  \
               &Vs[bb][0][0] + fc * 8);                                        \
    load_lds16(Vb + (size_t)rr_ * T_SEQ + (j1) * 64 + cc * 8,                  \
               &Vs[bb][1][0] + fc * 8);                                        \
  }

__device__ __forceinline__ void process_tile(
    int qt, const half_t* __restrict__ Qb, const half_t* __restrict__ Kb,
    const half_t* __restrict__ Vb, half_t* __restrict__ y, int b, int h,
    half_t (&Ks)[2][2][4096], half_t (&Vs)[2][2][4096],
    int wave, int lane, int g, int wq, int lane15, int quad) {
  int q0 = qt * 64;
  int qrow = q0 + wq * 16 + lane15;        // this wave's q column (S^T B-op n)
  half8 bq0 = *(const half8*)(Qb + (size_t)qrow * HD + quad * 8);
  half8 bq1 = *(const half8*)(Qb + (size_t)qrow * HD + 32 + quad * 8);
  f32x4 ot[4] = {};                        // O^T: d = nm*16+quad*4+r, q = lane15
  float l = 0.f;
  int R = (qt + 2) >> 1;                   // rounds = ceil((qt+1)/2)
  // hot loop: rounds 0..R-2, both groups unmasked
  for (int r = 0; r < R - 1; r++) {
    __syncthreads();                       // stage(r) DMA drained & visible
    int nj = 2 * (r + 1);
    int nj1 = (nj + 1 <= qt) ? nj + 1 : qt;  // clamp keeps address valid
    STAGE2((r + 1) & 1, nj, nj1);          // prefetch overlaps compute
    tile_mfma<false>(&Ks[r & 1][g][0], &Vs[r & 1][g][0], bq0, bq1, ot, l,
                     lane15, quad, 0);
  }
  // last round: group hitting kv==qt masks the diagonal; kv>qt skips
  __syncthreads();
  {
    int jtl = 2 * (R - 1) + g;
    const half_t* Kt = &Ks[(R - 1) & 1][g][0];
    const half_t* Vt = &Vs[(R - 1) & 1][g][0];
    if (jtl == qt)
      tile_mfma<true>(Kt, Vt, bq0, bq1, ot, l, lane15, quad, wq * 16 + lane15);
    else if (jtl < qt)
      tile_mfma<false>(Kt, Vt, bq0, bq1, ot, l, lane15, quad, 0);
  }
  // per-wave l: sum the 4 quads holding this q-column
  l += __shfl_xor(l, 16);
  l += __shfl_xor(l, 32);
  // cross-group combine via LDS (reuse K region, 17.4 KB <= 32 KB)
  __syncthreads();                         // all compute reads of K/V done
  float* cb = (float*)&Ks[0][0][0];
  int ci = (wq * 64 + lane) * 17;          // stride 17 floats: conflict-free
  if (g == 1) {
    #pragma unroll
    for (int nm = 0; nm < 4; nm++)
      #pragma unroll
      for (int r = 0; r < 4; r++) cb[ci + nm * 4 + r] = ot[nm][r];
    cb[ci + 16] = l;
  }
  __syncthreads();
  if (g == 0) {
    #pragma unroll
    for (int nm = 0; nm < 4; nm++)
      #pragma unroll
      for (int r = 0; r < 4; r++) ot[nm][r] += cb[ci + nm * 4 + r];
    l += cb[ci + 16];
    float invl = 1.0f / l;
    int t = q0 + wq * 16 + lane15;
    half_t* yr = y + (size_t)(b * T_SEQ + t) * C_DIM + h * 64;
    #pragma unroll
    for (int nm = 0; nm < 4; nm++) {
      half4 o4;
      #pragma unroll
      for (int r = 0; r < 4; r++) o4[r] = (half_t)(ot[nm][r] * invl);
      *(half4*)(yr + nm * 16 + quad * 4) = o4;   // 8B store
    }
  }
  __syncthreads();                         // combine region free before restage
}

__global__ __launch_bounds__(512) void k_flash(const half_t* __restrict__ Qg,
                                               const half_t* __restrict__ Kg,
                                               const half_t* __restrict__ Vg,
                                               half_t* __restrict__ y) {
  __shared__ half_t Ks[2][2][4096];
  __shared__ half_t Vs[2][2][4096];
  int bh = blockIdx.y;
  int b = bh >> 4, h = bh & 15;
  int x = blockIdx.x;                      // 0..15: q-tile pair (x, 31-x)
  int tid = threadIdx.x;
  int wave = tid >> 6, lane = tid & 63;
  int g = wave >> 2, wq = wave & 3;        // kv-parity group, q-warp in group
  int lane15 = lane & 15, quad = lane >> 4;
  const half_t* Qb = Qg + (size_t)bh * T_SEQ * HD;
  const half_t* Kb = Kg + (size_t)bh * T_SEQ * HD;
  const half_t* Vb = Vg + (size_t)bh * HD * T_SEQ;

  int qtA = x, qtB = 31 - x;
  STAGE2(0, 0, (qtA >= 1 ? 1 : 0));
  process_tile(qtA, Qb, Kb, Vb, y, b, h, Ks, Vs, wave, lane, g, wq, lane15, quad);
  STAGE2(0, 0, 1);                         // one un-overlapped stage per block
  process_tile(qtB, Qb, Kb, Vb, y, b, h, Ks, Vs, wave, lane, g, wq, lane15, quad);
  #undef STAGE2
}

extern "C" void kernel_launch(void* const* d_in, const int* in_sizes, int n_in,
                              void* d_out, int out_size, void* d_ws, size_t ws_size,
                              hipStream_t stream) {
  const float* x      = (const float*)d_in[0];
  const float* w_attn = (const float*)d_in[1];
  const float* b_attn = (const float*)d_in[2];
  const float* w_proj = (const float*)d_in[3];
  const float* b_proj = (const float*)d_in[4];
  float* out = (float*)d_out;

  char* ws = (char*)d_ws;
  const size_t MB = 1u << 20;
  half_t* xb  = (half_t*)(ws);             // 8 MB  x in f16
  half_t* wT  = (half_t*)(ws + 8 * MB);    // 6 MB  w_attn^T f16 [3072][1024]
  half_t* wpT = (half_t*)(ws + 14 * MB);   // 2 MB  w_proj^T f16 [1024][1024]
  half_t* Q   = (half_t*)(ws + 16 * MB);   // 8 MB  [bh][t][d]  (pre-scaled)
  half_t* Kb  = (half_t*)(ws + 24 * MB);   // 8 MB  [bh][t][d]
  half_t* Vt  = (half_t*)(ws + 32 * MB);   // 8 MB  [bh][d][t]
  half_t* qkv = (half_t*)(ws + 40 * MB);   // 24 MB f16 qkv
  half_t* y   = (half_t*)(ws + 40 * MB);   // aliases qkv (dead after k_rope)

  k_prep<<<4096 + 768 + 256, 256, 0, stream>>>(x, xb, w_attn, wT, w_proj, wpT);
  k_gemm<half_t, 128><<<dim3(N_QKV / 128, M_ROWS / 128), 256, 0, stream>>>(
      xb, wT, b_attn, qkv, M_ROWS, N_QKV, C_DIM);
  k_rope<<<dim3(T_SEQ / 64, B_SZ * N_HEADS), 256, 0, stream>>>(qkv, Q, Kb, Vt);
  k_flash<<<dim3(16, B_SZ * N_HEADS), 512, 0, stream>>>(Q, Kb, Vt, y);
  k_gemm<float, 64><<<dim3(C_DIM / 64, M_ROWS / 128), 256, 0, stream>>>(
      y, wpT, b_proj, out, M_ROWS, C_DIM, C_DIM);
}

// Round 3
// 185.100 us; speedup vs baseline: 1.0881x; 1.0502x over previous
//
#include <hip/hip_runtime.h>
#include <hip/hip_bf16.h>
#include <cmath>

typedef _Float16 half_t;
typedef half_t half4 __attribute__((ext_vector_type(4)));
typedef half_t half8 __attribute__((ext_vector_type(8)));
typedef float f32x4 __attribute__((ext_vector_type(4)));

#define N_HEADS 16
#define HD      64
#define T_SEQ   2048
#define B_SZ    2
#define C_DIM   1024
#define M_ROWS  (B_SZ * T_SEQ)   /* 4096 */
#define N_QKV   (3 * C_DIM)      /* 3072 */
#define QSCALE  0.18033688f      /* 0.125 * log2(e), folded into Q at rope */

__device__ inline void load_lds16(const half_t* g, half_t* l) {
  __builtin_amdgcn_global_load_lds(
      (const __attribute__((address_space(1))) void*)g,
      (__attribute__((address_space(3))) void*)l, 16, 0, 0);
}

// ---- fused prep: x->f16 cvt (blocks 0..4095), w_attn^T (..4863), w_proj^T ----
__global__ __launch_bounds__(256) void k_prep(const float* __restrict__ x,
                                              half_t* __restrict__ xb,
                                              const float* __restrict__ wa,
                                              half_t* __restrict__ wT,
                                              const float* __restrict__ wp,
                                              half_t* __restrict__ wpT) {
  __shared__ float tile[64][65];
  int bid = blockIdx.x, tid = threadIdx.x;
  if (bid < 4096) {
    int i = (bid * 256 + tid) * 4;
    float4 v = *(const float4*)(x + i);
    half_t o[4] = {(half_t)v.x, (half_t)v.y, (half_t)v.z, (half_t)v.w};
    *(ulong1*)(xb + i) = *(ulong1*)o;
    return;
  }
  const float* in; half_t* out; int K, N, id;
  if (bid < 4096 + 768) { id = bid - 4096; in = wa; out = wT;  K = 1024; N = 3072; }
  else                  { id = bid - 4864; in = wp; out = wpT; K = 1024; N = 1024; }
  int n0 = (id % (N / 64)) * 64, k0 = (id / (N / 64)) * 64;
  int tx = tid & 63, ty = tid >> 6;
  #pragma unroll
  for (int i = 0; i < 64; i += 4)
    tile[ty + i][tx] = in[(size_t)(k0 + ty + i) * N + n0 + tx];
  __syncthreads();
  #pragma unroll
  for (int i = 0; i < 64; i += 4) {
    int r = ty + i;
    out[(size_t)(n0 + r) * K + k0 + tx] = (half_t)tile[tx][r];
  }
}

// ------------- GEMM: C = A(f16,[M][K]) * Bt(f16,[N][K])^T + bias, OT out ----
// 128xTN tile, BK=64, global_load_lds width-16 into XOR-swizzled LDS.
template <typename OT, int TN>
__global__ __launch_bounds__(256) void k_gemm(const half_t* __restrict__ A,
                                              const half_t* __restrict__ Bt,
                                              const float* __restrict__ bias,
                                              OT* __restrict__ C,
                                              int M, int N, int K) {
  constexpr int NI = TN / 32;          // n-fragments per wave
  __shared__ half_t As[128 * 64];
  __shared__ half_t Bs[TN * 64];
  int tid = threadIdx.x;
  int wave = tid >> 6, lane = tid & 63;
  int lane15 = lane & 15, quad = lane >> 4;
  int wm = (wave >> 1) * 64, wn = (wave & 1) * (TN / 2);
  int bm0 = blockIdx.y * 128, bn0 = blockIdx.x * TN;
  f32x4 acc[4][NI] = {};

  for (int kb = 0; kb < K; kb += 64) {
    const half_t* Ag = A + (size_t)bm0 * K + kb;
    const half_t* Bg = Bt + (size_t)bn0 * K + kb;
    __syncthreads();
    #pragma unroll
    for (int p = 0; p < 4; p++) {
      int fc = wave * 4 * 64 + p * 64 + lane;
      int r = fc >> 3, c = (fc & 7) ^ (r & 7);
      load_lds16(Ag + (size_t)r * K + c * 8, As + (wave * 4 + p) * 512);
    }
    #pragma unroll
    for (int p = 0; p < NI; p++) {
      int fc = wave * NI * 64 + p * 64 + lane;
      int r = fc >> 3, c = (fc & 7) ^ (r & 7);
      load_lds16(Bg + (size_t)r * K + c * 8, Bs + (wave * NI + p) * 512);
    }
    __syncthreads();
    #pragma unroll
    for (int ks = 0; ks < 2; ks++) {
      half8 af[4], bf[NI];
      #pragma unroll
      for (int i = 0; i < 4; i++) {
        int Ra = wm + i * 16 + lane15;
        af[i] = *(const half8*)(As + Ra * 64 + ((ks * 4 + quad) ^ (Ra & 7)) * 8);
      }
      #pragma unroll
      for (int i = 0; i < NI; i++) {
        int Rb = wn + i * 16 + lane15;
        bf[i] = *(const half8*)(Bs + Rb * 64 + ((ks * 4 + quad) ^ (Rb & 7)) * 8);
      }
      #pragma unroll
      for (int mi = 0; mi < 4; mi++)
        #pragma unroll
        for (int ni = 0; ni < NI; ni++)
          acc[mi][ni] = __builtin_amdgcn_mfma_f32_16x16x32_f16(af[mi], bf[ni], acc[mi][ni], 0, 0, 0);
    }
  }
  #pragma unroll
  for (int mi = 0; mi < 4; mi++)
    #pragma unroll
    for (int ni = 0; ni < NI; ni++) {
      int n = bn0 + wn + ni * 16 + lane15;
      float bv = bias[n];
      int mrow = bm0 + wm + mi * 16 + quad * 4;
      #pragma unroll
      for (int r = 0; r < 4; r++)
        C[(size_t)(mrow + r) * N + n] = (OT)(acc[mi][ni][r] + bv);
    }
}

// ------------- RoPE + reorg (qkv f16); Q pre-scaled by 0.125*log2(e) -------------
__global__ __launch_bounds__(256) void k_rope(const half_t* __restrict__ qkv,
                                              half_t* __restrict__ Q,
                                              half_t* __restrict__ Ko,
                                              half_t* __restrict__ Vt) {
  __shared__ float vt[64][65];
  int bh = blockIdx.y;
  int b = bh >> 4, h = bh & 15;
  int t0 = blockIdx.x * 64;
  int tid = threadIdx.x;
  int trow = tid >> 5, i = tid & 31;           // 8 t-rows x 32 freq
  float inv = exp2f(-(float)i * (13.287712379549449f / 32.0f));
  #pragma unroll
  for (int p = 0; p < 8; p++) {
    int tloc = p * 8 + trow;
    int t = t0 + tloc;
    const half_t* row = qkv + (size_t)(b * T_SEQ + t) * N_QKV;
    float q1 = (float)row[h * 64 + i],        q2 = (float)row[h * 64 + i + 32];
    float k1 = (float)row[1024 + h * 64 + i], k2 = (float)row[1024 + h * 64 + i + 32];
    float v1 = (float)row[2048 + h * 64 + i], v2 = (float)row[2048 + h * 64 + i + 32];
    float s, c;
    sincosf((float)t * inv, &s, &c);
    size_t base = ((size_t)bh * T_SEQ + t) * HD;
    Q[base + i]       = (half_t)((q1 * c - q2 * s) * QSCALE);
    Q[base + i + 32]  = (half_t)((q1 * s + q2 * c) * QSCALE);
    Ko[base + i]      = (half_t)(k1 * c - k2 * s);
    Ko[base + i + 32] = (half_t)(k1 * s + k2 * c);
    vt[i][tloc]      = v1;
    vt[i + 32][tloc] = v2;
  }
  __syncthreads();
  int d = tid >> 6, tc = tid & 63;             // 4 d-rows x 64 t
  #pragma unroll
  for (int p = 0; p < 16; p++) {
    int dd = p * 4 + d;
    Vt[((size_t)bh * HD + dd) * T_SEQ + t0 + tc] = (half_t)vt[dd][tc];
  }
}

// ------------- causal flash v3: 128-q tiles, kv-split-2, 16 waves -------------
// R2 lesson: marginal cost of ISSUED staging bytes ~ 9 B/cyc/CU (VMEM service
// rate) -> staging-throughput-bound. R2 staged 16KB per 64x64 tile-unit
// (kv tile per 64 q-rows). v3 restores 8KB/unit (kv tile serves 128 q-rows)
// while KEEPING uniform rounds and kv-parity split:
//   16 waves: waves 0-7 = group 0 (even kv tiles), 8-15 = group 1 (odd).
//   Each group's 8 waves cover all 128 q rows. Rounds per 128-q tile = qt+1;
//   block does tiles x and 15-x sequentially -> 17 rounds for EVERY block.
//   Grid (8,32) = 256 blocks = exactly 1/CU, 16 waves/CU steady, no tail.
// Issued staging: 256 x 17 x 32KB = 139MB (R2: 278MB). LDS 64KB, 2-buffered.
// 2qt+2 kv tiles is even -> both groups always active; only diagonal round
// idles 4 of 16 waves (~1.5% waste). partial (O,l) ADD via LDS combine.
template <bool DIAG>
__device__ __forceinline__ void tile_mfma(const half_t* __restrict__ Kt,
                                          const half_t* __restrict__ Vt,
                                          half8 bq0, half8 bq1,
                                          f32x4 (&ot)[4], float& l,
                                          int lane15, int quad, int qloc) {
  f32x4 sacc[4];
  #pragma unroll
  for (int s = 0; s < 4; s++) {
    int R_ = s * 16 + lane15;
    half8 ak0 = *(const half8*)(Kt + R_ * 64 + ((quad) ^ (R_ & 7)) * 8);
    half8 ak1 = *(const half8*)(Kt + R_ * 64 + ((4 + quad) ^ (R_ & 7)) * 8);
    f32x4 z = {};
    z = __builtin_amdgcn_mfma_f32_16x16x32_f16(ak0, bq0, z, 0, 0, 0);
    sacc[s] = __builtin_amdgcn_mfma_f32_16x16x32_f16(ak1, bq1, z, 0, 0, 0);
  }
  #pragma unroll
  for (int s = 0; s < 4; s++) {
    half4 bp;
    #pragma unroll
    for (int r = 0; r < 4; r++) {
      float sv = sacc[s][r];
      if (DIAG && (s * 16 + quad * 4 + r > qloc)) sv = -1.0e30f;
      float p = exp2f(fminf(sv, 14.0f));
      l += p;
      bp[r] = (half_t)p;
    }
    #pragma unroll
    for (int nm = 0; nm < 4; nm++) {
      int Rv = nm * 16 + lane15;
      half4 av = *(const half4*)(Vt + Rv * 64 +
                                 ((2 * s + (quad >> 1)) ^ (Rv & 7)) * 8 +
                                 (quad & 1) * 4);
      ot[nm] = __builtin_amdgcn_mfma_f32_16x16x16f16(av, bp, ot[nm], 0, 0, 0);
    }
  }
}

// Stage kv tiles {2t, 2t+1} of K and V into buffer bb. 1024 threads, each
// issues 1 K + 1 V load_lds16 (16B): waves 0-7 serve group 0's tile (2t),
// waves 8-15 serve group 1's tile (2t+1). 32KB total per stage.
#define STAGE(bb, t_)                                                          \
  {                                                                            \
    int gS = wave >> 3;                                                        \
    int idx = (wave & 7) * 64 + lane;                                          \
    int rr_ = idx >> 3, cc = (idx & 7) ^ (rr_ & 7);                            \
    int j = 2 * (t_) + gS;                                                     \
    load_lds16(Kb + (size_t)(j * 64 + rr_) * HD + cc * 8,                      \
               &KV[bb][0][gS][0] + idx * 8);                                   \
    load_lds16(Vb + (size_t)rr_ * T_SEQ + j * 64 + cc * 8,                     \
               &KV[bb][1][gS][0] + idx * 8);                                   \
  }

__device__ __forceinline__ void process_tile(
    int qt, const half_t* __restrict__ Qb, const half_t* __restrict__ Kb,
    const half_t* __restrict__ Vb, half_t* __restrict__ y, int b, int h,
    half_t (&KV)[2][2][2][4096],
    int wave, int lane, int g, int wq, int lane15, int quad) {
  int q0 = qt * 128;
  int qrow = q0 + wq * 16 + lane15;        // this wave's q column (S^T B-op n)
  half8 bq0 = *(const half8*)(Qb + (size_t)qrow * HD + quad * 8);
  half8 bq1 = *(const half8*)(Qb + (size_t)qrow * HD + 32 + quad * 8);
  f32x4 ot[4] = {};                        // O^T: d = nm*16+quad*4+r, q = lane15
  float l = 0.f;
  int R = qt + 1;                          // rounds: group g does kv tile 2r+g
  // hot loop: rounds 0..R-2, both groups unmasked
  for (int r = 0; r < R - 1; r++) {
    __syncthreads();                       // stage(r) DMA drained & visible
    STAGE((r + 1) & 1, r + 1);             // prefetch overlaps compute
    tile_mfma<false>(&KV[r & 1][0][g][0], &KV[r & 1][1][g][0], bq0, bq1, ot, l,
                     lane15, quad, 0);
  }
  // last round (r = R-1): group 0 on tile 2qt (diag for wq<4, auto-full for
  // wq>=4 since qloc>=64>srow); group 1 on tile 2qt+1 (skip wq<4, diag wq>=4)
  __syncthreads();
  {
    int buf = (R - 1) & 1;
    const half_t* Kt = &KV[buf][0][g][0];
    const half_t* Vt = &KV[buf][1][g][0];
    if (g == 0)
      tile_mfma<true>(Kt, Vt, bq0, bq1, ot, l, lane15, quad, wq * 16 + lane15);
    else if (wq >= 4)
      tile_mfma<true>(Kt, Vt, bq0, bq1, ot, l, lane15, quad,
                      (wq - 4) * 16 + lane15);
  }
  // per-wave l: sum the 4 quads holding this q-column
  l += __shfl_xor(l, 16);
  l += __shfl_xor(l, 32);
  // cross-group combine via LDS (reuse KV region, 512*17*4B = 34.8KB <= 64KB)
  __syncthreads();                         // all compute reads of K/V done
  float* cb = (float*)&KV[0][0][0][0];
  int ci = (wq * 64 + lane) * 17;          // stride 17 floats: conflict-free
  if (g == 1) {
    #pragma unroll
    for (int nm = 0; nm < 4; nm++)
      #pragma unroll
      for (int r = 0; r < 4; r++) cb[ci + nm * 4 + r] = ot[nm][r];
    cb[ci + 16] = l;
  }
  __syncthreads();
  if (g == 0) {
    #pragma unroll
    for (int nm = 0; nm < 4; nm++)
      #pragma unroll
      for (int r = 0; r < 4; r++) ot[nm][r] += cb[ci + nm * 4 + r];
    l += cb[ci + 16];
    float invl = 1.0f / l;
    int t = q0 + wq * 16 + lane15;
    half_t* yr = y + (size_t)(b * T_SEQ + t) * C_DIM + h * 64;
    #pragma unroll
    for (int nm = 0; nm < 4; nm++) {
      half4 o4;
      #pragma unroll
      for (int r = 0; r < 4; r++) o4[r] = (half_t)(ot[nm][r] * invl);
      *(half4*)(yr + nm * 16 + quad * 4) = o4;   // 8B store
    }
  }
  __syncthreads();                         // combine region free before restage
}

__global__ __launch_bounds__(1024, 4) void k_flash(const half_t* __restrict__ Qg,
                                                   const half_t* __restrict__ Kg,
                                                   const half_t* __restrict__ Vg,
                                                   half_t* __restrict__ y) {
  __shared__ half_t KV[2][2][2][4096];     // [buf][K/V][grp][64*64]
  int bh = blockIdx.y;
  int b = bh >> 4, h = bh & 15;
  int x = blockIdx.x;                      // 0..7: q-tile pair (x, 15-x)
  int tid = threadIdx.x;
  int wave = tid >> 6, lane = tid & 63;
  int g = wave >> 3, wq = wave & 7;        // kv-parity group, q-warp in group
  int lane15 = lane & 15, quad = lane >> 4;
  const half_t* Qb = Qg + (size_t)bh * T_SEQ * HD;
  const half_t* Kb = Kg + (size_t)bh * T_SEQ * HD;
  const half_t* Vb = Vg + (size_t)bh * HD * T_SEQ;

  int qtA = x, qtB = 15 - x;
  STAGE(0, 0);
  process_tile(qtA, Qb, Kb, Vb, y, b, h, KV, wave, lane, g, wq, lane15, quad);
  STAGE(0, 0);                             // one un-overlapped stage per block
  process_tile(qtB, Qb, Kb, Vb, y, b, h, KV, wave, lane, g, wq, lane15, quad);
  #undef STAGE
}

extern "C" void kernel_launch(void* const* d_in, const int* in_sizes, int n_in,
                              void* d_out, int out_size, void* d_ws, size_t ws_size,
                              hipStream_t stream) {
  const float* x      = (const float*)d_in[0];
  const float* w_attn = (const float*)d_in[1];
  const float* b_attn = (const float*)d_in[2];
  const float* w_proj = (const float*)d_in[3];
  const float* b_proj = (const float*)d_in[4];
  float* out = (float*)d_out;

  char* ws = (char*)d_ws;
  const size_t MB = 1u << 20;
  half_t* xb  = (half_t*)(ws);             // 8 MB  x in f16
  half_t* wT  = (half_t*)(ws + 8 * MB);    // 6 MB  w_attn^T f16 [3072][1024]
  half_t* wpT = (half_t*)(ws + 14 * MB);   // 2 MB  w_proj^T f16 [1024][1024]
  half_t* Q   = (half_t*)(ws + 16 * MB);   // 8 MB  [bh][t][d]  (pre-scaled)
  half_t* Kb  = (half_t*)(ws + 24 * MB);   // 8 MB  [bh][t][d]
  half_t* Vt  = (half_t*)(ws + 32 * MB);   // 8 MB  [bh][d][t]
  half_t* qkv = (half_t*)(ws + 40 * MB);   // 24 MB f16 qkv
  half_t* y   = (half_t*)(ws + 40 * MB);   // aliases qkv (dead after k_rope)

  k_prep<<<4096 + 768 + 256, 256, 0, stream>>>(x, xb, w_attn, wT, w_proj, wpT);
  k_gemm<half_t, 128><<<dim3(N_QKV / 128, M_ROWS / 128), 256, 0, stream>>>(
      xb, wT, b_attn, qkv, M_ROWS, N_QKV, C_DIM);
  k_rope<<<dim3(T_SEQ / 64, B_SZ * N_HEADS), 256, 0, stream>>>(qkv, Q, Kb, Vt);
  k_flash<<<dim3(8, B_SZ * N_HEADS), 1024, 0, stream>>>(Q, Kb, Vt, y);
  k_gemm<float, 64><<<dim3(C_DIM / 64, M_ROWS / 128), 256, 0, stream>>>(
      y, wpT, b_proj, out, M_ROWS, C_DIM, C_DIM);
}